// Round 2
// baseline (163.138 us; speedup 1.0000x reference)
//
#include <hip/hip_runtime.h>
#include <hip/hip_bf16.h>
#include <math.h>

// Problem constants: N=4, L=1024, D=1024, H=16, HD=64, HIST=128, SCALE=32
// Faithful-bug structure: attention[n,l,h,d] = (sum_q scores[n,h,q,l]) * v[n,l,h,d]
// => only column sums w[n,h,l] of softmax needed.
// Energy trick: E = Xq (Wq^T Wk/32) Xk^T = Xq . kk2^T with kk2 = K.(M^T).
// Round 12:
//  k_out -> 128x128 tiles, 4 waves each owning a 64x64 quadrant (4x4 frags).
//  Rationale: old 128x64 wave=2x4 frags read 12 ds_read_b128 per 16 MFMA
//  (LDS-read-BW bound ~2-5x over MFMA demand); 4x4 frags read 16 per 32
//  MFMA (1.5x better FLOP/LDS-byte) and A-tile L2 re-reads halve (16->8).
//  Staging map stays the linear tid*16B pattern (gload_lds-safe); MFMA
//  k-order preserved -> bit-identical output. Grid 256, LDS 64KB dbuf.

using short8 = __attribute__((ext_vector_type(8))) short;
using f32x4  = __attribute__((ext_vector_type(4))) float;

__device__ __forceinline__ unsigned short f2bf(float x) {
    unsigned u = __float_as_uint(x);
    u += 0x7FFFu + ((u >> 16) & 1u);      // round-to-nearest-even
    return (unsigned short)(u >> 16);
}

// ---------------------------------------------------------------------------
// K0 (k_stage), grid 2064:
//  b 0..1023   : kk2p[nh][l][e] = bf16( sum_f keys[n,l,h*64+f] * M[e,f] ),
//                M computed in-block via MFMA (A=Wq^T, B=Wk^T frags from global)
//  b 1024..2047: wob = bf16(Wo); first 256 of these also zero w
//  b 2048..2063: Wvb = bf16(Wv)
// ---------------------------------------------------------------------------
__global__ __launch_bounds__(256) void k_stage(const float* __restrict__ keys,
                                               const float* __restrict__ Wq,
                                               const float* __restrict__ Wk,
                                               const float* __restrict__ Wv,
                                               const float4* __restrict__ Wo4,
                                               unsigned short* __restrict__ kk2p,
                                               ushort4* __restrict__ wob4,
                                               unsigned short* __restrict__ Wvb,
                                               float* __restrict__ w) {
    __shared__ unsigned short Ml[64 * 64];    // 8 KB, M[e][f] bf16 (kp blocks)

    const int b = blockIdx.x, tid = threadIdx.x;

    if (b < 1024) {
        // ---------------- kp: kk2 = K @ M^T ----------------
        const int wv = tid >> 6, lane = tid & 63;
        const int m = lane & 15, q4 = lane >> 4, ksel = q4 * 8;

        // phase M: D[e][f] = sum_d Wq[d][e]*Wk[d][f]
        {
            short8 aM0, aM1;
#pragma unroll
            for (int j = 0; j < 8; ++j) {
                aM0[j] = (short)f2bf(Wq[(ksel + j) * 64 + wv * 16 + m]);
                aM1[j] = (short)f2bf(Wq[(32 + ksel + j) * 64 + wv * 16 + m]);
            }
#pragma unroll
            for (int fc = 0; fc < 4; ++fc) {
                short8 bM0, bM1;
#pragma unroll
                for (int j = 0; j < 8; ++j) {
                    bM0[j] = (short)f2bf(Wk[(ksel + j) * 64 + fc * 16 + m]);
                    bM1[j] = (short)f2bf(Wk[(32 + ksel + j) * 64 + fc * 16 + m]);
                }
                f32x4 a = f32x4{0.f, 0.f, 0.f, 0.f};
                a = __builtin_amdgcn_mfma_f32_16x16x32_bf16(aM0, bM0, a, 0, 0, 0);
                a = __builtin_amdgcn_mfma_f32_16x16x32_bf16(aM1, bM1, a, 0, 0, 0);
#pragma unroll
                for (int r = 0; r < 4; ++r)
                    Ml[(wv * 16 + q4 * 4 + r) * 64 + fc * 16 + m] =
                        f2bf(a[r] * (1.0f / 32.0f));
            }
        }
        __syncthreads();

        // phase kp: rows R0..R0+63 of keys-as-(65536,64)
        const long R0 = (long)b * 64;
        const float* ka = keys + (R0 + wv * 16 + m) * 64;
        short8 af[2];
#pragma unroll
        for (int ch = 0; ch < 2; ++ch) {
            float4 x0 = *reinterpret_cast<const float4*>(ka + ch * 32 + ksel);
            float4 x1 = *reinterpret_cast<const float4*>(ka + ch * 32 + ksel + 4);
            short8 a;
            a[0] = (short)f2bf(x0.x); a[1] = (short)f2bf(x0.y);
            a[2] = (short)f2bf(x0.z); a[3] = (short)f2bf(x0.w);
            a[4] = (short)f2bf(x1.x); a[5] = (short)f2bf(x1.y);
            a[6] = (short)f2bf(x1.z); a[7] = (short)f2bf(x1.w);
            af[ch] = a;
        }

        f32x4 acc[4];
#pragma unroll
        for (int fc = 0; fc < 4; ++fc) {
            acc[fc] = f32x4{0.f, 0.f, 0.f, 0.f};
#pragma unroll
            for (int ch = 0; ch < 2; ++ch) {
                short8 bf = *reinterpret_cast<const short8*>(
                    &Ml[(fc * 16 + m) * 64 + ch * 32 + ksel]);
                acc[fc] = __builtin_amdgcn_mfma_f32_16x16x32_bf16(af[ch], bf, acc[fc], 0, 0, 0);
            }
        }

        const long rowb = R0 + wv * 16 + (lane >> 4) * 4;
#pragma unroll
        for (int reg = 0; reg < 4; ++reg) {
            long rg = rowb + reg;
            int hh = (int)(rg & 15);
            int ll = (int)((rg >> 4) & 1023);
            int nn = (int)(rg >> 14);
            unsigned short* orow = kk2p + ((size_t)((nn * 16 + hh) * 1024 + ll)) * 64;
#pragma unroll
            for (int fc = 0; fc < 4; ++fc)
                orow[fc * 16 + m] = f2bf(acc[fc][reg]);
        }
    } else if (b < 2048) {
        // ---------------- Wo -> bf16 (+ zero w) ----------------
        const int bb = b - 1024;
        int idx = bb * 256 + tid;             // 262144 float4s
        float4 v = Wo4[idx];
        ushort4 o; o.x = f2bf(v.x); o.y = f2bf(v.y);
        o.z = f2bf(v.z); o.w = f2bf(v.w);
        wob4[idx] = o;
        if (bb < 256) w[bb * 256 + tid] = 0.f;
    } else {
        // ---------------- Wv -> bf16 ----------------
        int idx = (b - 2048) * 256 + tid;     // 4096
        Wvb[idx] = f2bf(Wv[idx]);
    }
}

// ---------------------------------------------------------------------------
// K1 (k_w2): per (nh, 64-row tile): energy 64x192 via MFMA, banded softmax,
// column sums -> w atomics. A-frags gathered DIRECTLY from query f32
// (4x float4/lane, full 256B row-slices consumed -> 100% line efficiency);
// f2bf in-register is bit-identical to the old qb staging path.
// ---------------------------------------------------------------------------
__global__ __launch_bounds__(256) void k_w2(const float* __restrict__ query,
                                            const unsigned short* __restrict__ kk2p,
                                            float* __restrict__ w) {
    __shared__ float wloc[192];

    const int tid  = threadIdx.x;
    const int b    = blockIdx.x;          // 1024
    const int nh   = b & 63;              // swizzle: nh fast, tile slow
    const int tile = b >> 6;
    const int t0   = tile * 64;
    const int h    = nh & 15, n = nh >> 4;

    if (tid < 192) wloc[tid] = 0.f;
    __syncthreads();

    const int wv = tid >> 6, lane = tid & 63;
    const int m = lane & 15, q4 = lane >> 4, ksel = q4 * 8;

    const float* qrow = query +
        ((size_t)(n * 1024 + t0 + wv * 16 + m)) * 1024 + h * 64;
    float4 x0 = *reinterpret_cast<const float4*>(qrow + ksel);
    float4 x1 = *reinterpret_cast<const float4*>(qrow + ksel + 4);
    float4 x2 = *reinterpret_cast<const float4*>(qrow + 32 + ksel);
    float4 x3 = *reinterpret_cast<const float4*>(qrow + 32 + ksel + 4);
    short8 af0, af1;
    af0[0] = (short)f2bf(x0.x); af0[1] = (short)f2bf(x0.y);
    af0[2] = (short)f2bf(x0.z); af0[3] = (short)f2bf(x0.w);
    af0[4] = (short)f2bf(x1.x); af0[5] = (short)f2bf(x1.y);
    af0[6] = (short)f2bf(x1.z); af0[7] = (short)f2bf(x1.w);
    af1[0] = (short)f2bf(x2.x); af1[1] = (short)f2bf(x2.y);
    af1[2] = (short)f2bf(x2.z); af1[3] = (short)f2bf(x2.w);
    af1[4] = (short)f2bf(x3.x); af1[5] = (short)f2bf(x3.y);
    af1[6] = (short)f2bf(x3.z); af1[7] = (short)f2bf(x3.w);

    const unsigned short* kb = kk2p + (size_t)nh * 1024 * 64;

    f32x4 acc[12];
#pragma unroll
    for (int ni = 0; ni < 12; ++ni) {         // FULL unroll: compile-time idx
        int l = t0 - 127 + ni * 16 + m;
        int lc = min(max(l, 0), 1023);
        const unsigned short* kp = kb + (size_t)lc * 64 + ksel;
        short8 b0 = *reinterpret_cast<const short8*>(kp);
        short8 b1 = *reinterpret_cast<const short8*>(kp + 32);
        f32x4 a = f32x4{0.f, 0.f, 0.f, 0.f};
        a = __builtin_amdgcn_mfma_f32_16x16x32_bf16(af0, b0, a, 0, 0, 0);
        a = __builtin_amdgcn_mfma_f32_16x16x32_bf16(af1, b1, a, 0, 0, 0);
        acc[ni] = a;
    }

    // banded softmax: col c = ni*16+m, local row = wv*16 + q4*4 + reg
    const int rbase = wv * 16 + q4 * 4;
    float rs[4] = {0.f, 0.f, 0.f, 0.f};
#pragma unroll
    for (int ni = 0; ni < 12; ++ni) {
        const int c = ni * 16 + m;
#pragma unroll
        for (int reg = 0; reg < 4; ++reg) {
            const int rlw = rbase + reg;
            bool valid = (c >= rlw) && (c <= rlw + 127) && (c + t0 >= 127);
            float e = valid ? __expf(acc[ni][reg]) : 0.f;
            acc[ni][reg] = e;
            rs[reg] += e;
        }
    }
#pragma unroll
    for (int reg = 0; reg < 4; ++reg) {
#pragma unroll
        for (int mm = 1; mm < 16; mm <<= 1) rs[reg] += __shfl_xor(rs[reg], mm);
        rs[reg] = 1.0f / rs[reg];             // diagonal always valid -> > 0
    }
#pragma unroll
    for (int ni = 0; ni < 12; ++ni) {
        float cs = acc[ni][0] * rs[0] + acc[ni][1] * rs[1] +
                   acc[ni][2] * rs[2] + acc[ni][3] * rs[3];
        cs += __shfl_xor(cs, 16);
        cs += __shfl_xor(cs, 32);
        if (lane < 16) atomicAdd(&wloc[ni * 16 + m], cs);
    }
    __syncthreads();

    for (int c = tid; c < 192; c += 256) {
        int l = t0 - 127 + c;
        if (l >= 0 && l < 1024)
            atomicAdd(&w[(size_t)nh * 1024 + l], wloc[c]);
    }
}

// ---------------------------------------------------------------------------
// K2: apb[row][d] = bf16( w_scale(row) * sum_e values[row][e] * Wv[d][e] )
// ---------------------------------------------------------------------------
__global__ __launch_bounds__(256) void k_ap2(const float* __restrict__ values,
                                             const unsigned short* __restrict__ Wvb,
                                             const float* __restrict__ w,
                                             unsigned short* __restrict__ apb) {
    const int tid = threadIdx.x;
    const long R0 = (long)blockIdx.x * 64;    // 1024 blocks
    const int wv = tid >> 6, lane = tid & 63;
    const int m = lane & 15, ksel = (lane >> 4) * 8;

    const float* va = values + (R0 + wv * 16 + m) * 64;
    short8 af[2];
#pragma unroll
    for (int ch = 0; ch < 2; ++ch) {
        float4 x0 = *reinterpret_cast<const float4*>(va + ch * 32 + ksel);
        float4 x1 = *reinterpret_cast<const float4*>(va + ch * 32 + ksel + 4);
        short8 a;
        a[0] = (short)f2bf(x0.x); a[1] = (short)f2bf(x0.y);
        a[2] = (short)f2bf(x0.z); a[3] = (short)f2bf(x0.w);
        a[4] = (short)f2bf(x1.x); a[5] = (short)f2bf(x1.y);
        a[6] = (short)f2bf(x1.z); a[7] = (short)f2bf(x1.w);
        af[ch] = a;
    }

    f32x4 acc[4];
#pragma unroll
    for (int dc = 0; dc < 4; ++dc) {
        acc[dc] = f32x4{0.f, 0.f, 0.f, 0.f};
#pragma unroll
        for (int ch = 0; ch < 2; ++ch) {
            short8 bf = *reinterpret_cast<const short8*>(
                Wvb + (size_t)(dc * 16 + m) * 64 + ch * 32 + ksel);
            acc[dc] = __builtin_amdgcn_mfma_f32_16x16x32_bf16(af[ch], bf, acc[dc], 0, 0, 0);
        }
    }

    const long rowb = R0 + wv * 16 + (lane >> 4) * 4;
    float wf[4];
#pragma unroll
    for (int reg = 0; reg < 4; ++reg) {
        long rg = rowb + reg;
        int hh = (int)(rg & 15);
        int ll = (int)((rg >> 4) & 1023);
        int nn = (int)(rg >> 14);
        wf[reg] = w[((size_t)(nn * 16 + hh) << 10) + ll];
    }
#pragma unroll
    for (int dc = 0; dc < 4; ++dc)
#pragma unroll
        for (int reg = 0; reg < 4; ++reg)
            apb[(size_t)(rowb + reg) * 64 + dc * 16 + m] = f2bf(acc[dc][reg] * wf[reg]);
}

// ---------------------------------------------------------------------------
// K3: out = ap (4096x1024 bf16) @ Wo^T (bf16) + bo, f32 out.
// 128x128 tiles, grid 256 (strip-fast swizzle), 4 waves each owning a 64x64
// quadrant (4x4 16x16 frags). BK=64 as two 128x32 halves per operand.
// 2-phase double-buffer: stage kt+1 before computing kt, ONE __syncthreads
// per K-step (implicit vmcnt(0)+lgkmcnt(0) is the required wait).
// LDS 64KB. Staging = linear tid*16B map (gload_lds-safe). MFMA k-order
// (hh=0,1 per kt, kt ascending) preserved -> bit-identical output.
// ---------------------------------------------------------------------------
__global__ __launch_bounds__(256) void k_out_mfma(
    const unsigned short* __restrict__ apb,
    const unsigned short* __restrict__ wob,
    const float* __restrict__ bo,
    float* __restrict__ out) {
    __shared__ unsigned short As[2][2][128 * 32];   // [buf][half] 4 x 8 KB
    __shared__ unsigned short Bs[2][2][128 * 32];   // [buf][half] 4 x 8 KB

    const int tid  = threadIdx.x;
    const int wv   = tid >> 6;
    const int lane = tid & 63;
    const int m    = lane & 15;
    const int wr   = wv >> 1;       // wave row-half (0..1)
    const int wc   = wv & 1;        // wave col-half (0..1)

    const int by = blockIdx.x & 31;   // row strip (swizzle: strip fast)
    const int bx = blockIdx.x >> 5;   // 8 col tiles (128 cols)
    const long arow0 = (long)by * 128;
    const int  bcol0 = bx * 128;

    f32x4 acc[4][4];
#pragma unroll
    for (int mi = 0; mi < 4; ++mi)
#pragma unroll
        for (int ni = 0; ni < 4; ++ni) acc[mi][ni] = f32x4{0.f, 0.f, 0.f, 0.f};

    const int r0s = tid >> 2;         // 0..63
    const int kks = (tid & 3) * 8;

    // stage one BK=64 tile (two 32-halves) into buffer `buf`
    auto stage = [&](int buf, int kt) {
        const int k0 = kt * 64;
#pragma unroll
        for (int hh = 0; hh < 2; ++hh) {
            const int kh = k0 + hh * 32;
#pragma unroll
            for (int i = 0; i < 2; ++i) {
                const unsigned short* ga =
                    apb + (arow0 + i * 64 + r0s) * 1024 + kh + kks;
                __builtin_amdgcn_global_load_lds(
                    (const __attribute__((address_space(1))) unsigned int*)ga,
                    (__attribute__((address_space(3))) unsigned int*)&As[buf][hh][i * 2048 + wv * 512],
                    16, 0, 0);
                const unsigned short* gb =
                    wob + (size_t)(bcol0 + i * 64 + r0s) * 1024 + kh + kks;
                __builtin_amdgcn_global_load_lds(
                    (const __attribute__((address_space(1))) unsigned int*)gb,
                    (__attribute__((address_space(3))) unsigned int*)&Bs[buf][hh][i * 2048 + wv * 512],
                    16, 0, 0);
            }
        }
    };

    stage(0, 0);
    __syncthreads();                  // vmcnt(0): tile 0 landed

    const int koff = (lane >> 4) * 8;
    int cur = 0;
    for (int kt = 0; kt < 16; ++kt) {
        if (kt < 15) stage(cur ^ 1, kt + 1);   // prefetch next tile (in flight)

        short8 af[4][2], bf[4][2];
#pragma unroll
        for (int hh = 0; hh < 2; ++hh) {
#pragma unroll
            for (int mi = 0; mi < 4; ++mi)
                af[mi][hh] = *reinterpret_cast<const short8*>(
                    &As[cur][hh][(wr * 64 + mi * 16 + m) * 32 + koff]);
#pragma unroll
            for (int ni = 0; ni < 4; ++ni)
                bf[ni][hh] = *reinterpret_cast<const short8*>(
                    &Bs[cur][hh][(wc * 64 + ni * 16 + m) * 32 + koff]);
        }
#pragma unroll
        for (int mi = 0; mi < 4; ++mi)
#pragma unroll
            for (int ni = 0; ni < 4; ++ni) {
                acc[mi][ni] = __builtin_amdgcn_mfma_f32_16x16x32_bf16(
                    af[mi][0], bf[ni][0], acc[mi][ni], 0, 0, 0);
                acc[mi][ni] = __builtin_amdgcn_mfma_f32_16x16x32_bf16(
                    af[mi][1], bf[ni][1], acc[mi][ni], 0, 0, 0);
            }
        __syncthreads();              // drains vmcnt(0) (next tile) + lgkmcnt
        cur ^= 1;
    }

    const int rowq = (lane >> 4) * 4;
#pragma unroll
    for (int ni = 0; ni < 4; ++ni) {
        const int col = bcol0 + wc * 64 + ni * 16 + m;
        const float bias = bo[col];
#pragma unroll
        for (int mi = 0; mi < 4; ++mi) {
            const int row = (int)arow0 + wr * 64 + mi * 16 + rowq;
#pragma unroll
            for (int r = 0; r < 4; ++r)
                out[(size_t)(row + r) * 1024 + col] = acc[mi][ni][r] + bias;
        }
    }
}

// ---------------------------------------------------------------------------
extern "C" void kernel_launch(void* const* d_in, const int* in_sizes, int n_in,
                              void* d_out, int out_size, void* d_ws, size_t ws_size,
                              hipStream_t stream) {
    const float* values = (const float*)d_in[0];
    const float* keys   = (const float*)d_in[1];
    const float* query  = (const float*)d_in[2];
    const float* Wv     = (const float*)d_in[4];
    const float* Wk     = (const float*)d_in[5];
    const float* Wq     = (const float*)d_in[6];
    const float* Wo     = (const float*)d_in[7];
    const float* bo     = (const float*)d_in[8];
    float* out = (float*)d_out;

    // workspace layout (~18.3 MB of the 256 MiB ws; no overlays — r3 lesson):
    float* w             = (float*)d_ws;                 // 65536 f32   (256 KB)
    unsigned short* Wvb  = (unsigned short*)(w + 65536); // 4096 bf16   (8 KB)
    unsigned short* wob  = Wvb + 4096;                   // 1M bf16     (2 MB)
    unsigned short* kk2p = wob + 1024 * 1024;            // 4M bf16     (8 MB)
    unsigned short* apb  = kk2p + 64 * 1024 * 64;        // 4M bf16     (8 MB)

    k_stage<<<2064, 256, 0, stream>>>(keys, Wq, Wk, Wv, (const float4*)Wo,
                                      kk2p, (ushort4*)wob, Wvb, w);
    k_w2<<<1024, 256, 0, stream>>>(query, kk2p, w);
    k_ap2<<<1024, 256, 0, stream>>>(values, Wvb, w, apb);
    k_out_mfma<<<256, 256, 0, stream>>>(apb, wob, bo, out);
}

// Round 3
// 157.694 us; speedup vs baseline: 1.0345x; 1.0345x over previous
//
#include <hip/hip_runtime.h>
#include <hip/hip_bf16.h>
#include <math.h>

// Problem constants: N=4, L=1024, D=1024, H=16, HD=64, HIST=128, SCALE=32
// Faithful-bug structure: attention[n,l,h,d] = (sum_q scores[n,h,q,l]) * v[n,l,h,d]
// => only column sums w[n,h,l] of softmax needed.
// Energy trick: E = Xq (Wq^T Wk/32) Xk^T = Xq . kk2^T with kk2 = K.(M^T).
// Round 13: REVERT k_out to the R1-proven 128x64/grid-512 dbuf version.
//  R2 lesson: 128x128 tiles force grid 256 = 1 block/CU; the barrier drain
//  (vmcnt(0)+s_barrier) then has no co-resident block to hide it -> +7us.
//  128x64 @ 512 blocks = 2 blocks/CU keeps the drain overlapped.

using short8 = __attribute__((ext_vector_type(8))) short;
using f32x4  = __attribute__((ext_vector_type(4))) float;

__device__ __forceinline__ unsigned short f2bf(float x) {
    unsigned u = __float_as_uint(x);
    u += 0x7FFFu + ((u >> 16) & 1u);      // round-to-nearest-even
    return (unsigned short)(u >> 16);
}

// ---------------------------------------------------------------------------
// K0 (k_stage), grid 2064:
//  b 0..1023   : kk2p[nh][l][e] = bf16( sum_f keys[n,l,h*64+f] * M[e,f] ),
//                M computed in-block via MFMA (A=Wq^T, B=Wk^T frags from global)
//  b 1024..2047: wob = bf16(Wo); first 256 of these also zero w
//  b 2048..2063: Wvb = bf16(Wv)
// ---------------------------------------------------------------------------
__global__ __launch_bounds__(256) void k_stage(const float* __restrict__ keys,
                                               const float* __restrict__ Wq,
                                               const float* __restrict__ Wk,
                                               const float* __restrict__ Wv,
                                               const float4* __restrict__ Wo4,
                                               unsigned short* __restrict__ kk2p,
                                               ushort4* __restrict__ wob4,
                                               unsigned short* __restrict__ Wvb,
                                               float* __restrict__ w) {
    __shared__ unsigned short Ml[64 * 64];    // 8 KB, M[e][f] bf16 (kp blocks)

    const int b = blockIdx.x, tid = threadIdx.x;

    if (b < 1024) {
        // ---------------- kp: kk2 = K @ M^T ----------------
        const int wv = tid >> 6, lane = tid & 63;
        const int m = lane & 15, q4 = lane >> 4, ksel = q4 * 8;

        // phase M: D[e][f] = sum_d Wq[d][e]*Wk[d][f]
        {
            short8 aM0, aM1;
#pragma unroll
            for (int j = 0; j < 8; ++j) {
                aM0[j] = (short)f2bf(Wq[(ksel + j) * 64 + wv * 16 + m]);
                aM1[j] = (short)f2bf(Wq[(32 + ksel + j) * 64 + wv * 16 + m]);
            }
#pragma unroll
            for (int fc = 0; fc < 4; ++fc) {
                short8 bM0, bM1;
#pragma unroll
                for (int j = 0; j < 8; ++j) {
                    bM0[j] = (short)f2bf(Wk[(ksel + j) * 64 + fc * 16 + m]);
                    bM1[j] = (short)f2bf(Wk[(32 + ksel + j) * 64 + fc * 16 + m]);
                }
                f32x4 a = f32x4{0.f, 0.f, 0.f, 0.f};
                a = __builtin_amdgcn_mfma_f32_16x16x32_bf16(aM0, bM0, a, 0, 0, 0);
                a = __builtin_amdgcn_mfma_f32_16x16x32_bf16(aM1, bM1, a, 0, 0, 0);
#pragma unroll
                for (int r = 0; r < 4; ++r)
                    Ml[(wv * 16 + q4 * 4 + r) * 64 + fc * 16 + m] =
                        f2bf(a[r] * (1.0f / 32.0f));
            }
        }
        __syncthreads();

        // phase kp: rows R0..R0+63 of keys-as-(65536,64)
        const long R0 = (long)b * 64;
        const float* ka = keys + (R0 + wv * 16 + m) * 64;
        short8 af[2];
#pragma unroll
        for (int ch = 0; ch < 2; ++ch) {
            float4 x0 = *reinterpret_cast<const float4*>(ka + ch * 32 + ksel);
            float4 x1 = *reinterpret_cast<const float4*>(ka + ch * 32 + ksel + 4);
            short8 a;
            a[0] = (short)f2bf(x0.x); a[1] = (short)f2bf(x0.y);
            a[2] = (short)f2bf(x0.z); a[3] = (short)f2bf(x0.w);
            a[4] = (short)f2bf(x1.x); a[5] = (short)f2bf(x1.y);
            a[6] = (short)f2bf(x1.z); a[7] = (short)f2bf(x1.w);
            af[ch] = a;
        }

        f32x4 acc[4];
#pragma unroll
        for (int fc = 0; fc < 4; ++fc) {
            acc[fc] = f32x4{0.f, 0.f, 0.f, 0.f};
#pragma unroll
            for (int ch = 0; ch < 2; ++ch) {
                short8 bf = *reinterpret_cast<const short8*>(
                    &Ml[(fc * 16 + m) * 64 + ch * 32 + ksel]);
                acc[fc] = __builtin_amdgcn_mfma_f32_16x16x32_bf16(af[ch], bf, acc[fc], 0, 0, 0);
            }
        }

        const long rowb = R0 + wv * 16 + (lane >> 4) * 4;
#pragma unroll
        for (int reg = 0; reg < 4; ++reg) {
            long rg = rowb + reg;
            int hh = (int)(rg & 15);
            int ll = (int)((rg >> 4) & 1023);
            int nn = (int)(rg >> 14);
            unsigned short* orow = kk2p + ((size_t)((nn * 16 + hh) * 1024 + ll)) * 64;
#pragma unroll
            for (int fc = 0; fc < 4; ++fc)
                orow[fc * 16 + m] = f2bf(acc[fc][reg]);
        }
    } else if (b < 2048) {
        // ---------------- Wo -> bf16 (+ zero w) ----------------
        const int bb = b - 1024;
        int idx = bb * 256 + tid;             // 262144 float4s
        float4 v = Wo4[idx];
        ushort4 o; o.x = f2bf(v.x); o.y = f2bf(v.y);
        o.z = f2bf(v.z); o.w = f2bf(v.w);
        wob4[idx] = o;
        if (bb < 256) w[bb * 256 + tid] = 0.f;
    } else {
        // ---------------- Wv -> bf16 ----------------
        int idx = (b - 2048) * 256 + tid;     // 4096
        Wvb[idx] = f2bf(Wv[idx]);
    }
}

// ---------------------------------------------------------------------------
// K1 (k_w2): per (nh, 64-row tile): energy 64x192 via MFMA, banded softmax,
// column sums -> w atomics. A-frags gathered DIRECTLY from query f32
// (4x float4/lane, full 256B row-slices consumed -> 100% line efficiency);
// f2bf in-register is bit-identical to the old qb staging path.
// ---------------------------------------------------------------------------
__global__ __launch_bounds__(256) void k_w2(const float* __restrict__ query,
                                            const unsigned short* __restrict__ kk2p,
                                            float* __restrict__ w) {
    __shared__ float wloc[192];

    const int tid  = threadIdx.x;
    const int b    = blockIdx.x;          // 1024
    const int nh   = b & 63;              // swizzle: nh fast, tile slow
    const int tile = b >> 6;
    const int t0   = tile * 64;
    const int h    = nh & 15, n = nh >> 4;

    if (tid < 192) wloc[tid] = 0.f;
    __syncthreads();

    const int wv = tid >> 6, lane = tid & 63;
    const int m = lane & 15, q4 = lane >> 4, ksel = q4 * 8;

    const float* qrow = query +
        ((size_t)(n * 1024 + t0 + wv * 16 + m)) * 1024 + h * 64;
    float4 x0 = *reinterpret_cast<const float4*>(qrow + ksel);
    float4 x1 = *reinterpret_cast<const float4*>(qrow + ksel + 4);
    float4 x2 = *reinterpret_cast<const float4*>(qrow + 32 + ksel);
    float4 x3 = *reinterpret_cast<const float4*>(qrow + 32 + ksel + 4);
    short8 af0, af1;
    af0[0] = (short)f2bf(x0.x); af0[1] = (short)f2bf(x0.y);
    af0[2] = (short)f2bf(x0.z); af0[3] = (short)f2bf(x0.w);
    af0[4] = (short)f2bf(x1.x); af0[5] = (short)f2bf(x1.y);
    af0[6] = (short)f2bf(x1.z); af0[7] = (short)f2bf(x1.w);
    af1[0] = (short)f2bf(x2.x); af1[1] = (short)f2bf(x2.y);
    af1[2] = (short)f2bf(x2.z); af1[3] = (short)f2bf(x2.w);
    af1[4] = (short)f2bf(x3.x); af1[5] = (short)f2bf(x3.y);
    af1[6] = (short)f2bf(x3.z); af1[7] = (short)f2bf(x3.w);

    const unsigned short* kb = kk2p + (size_t)nh * 1024 * 64;

    f32x4 acc[12];
#pragma unroll
    for (int ni = 0; ni < 12; ++ni) {         // FULL unroll: compile-time idx
        int l = t0 - 127 + ni * 16 + m;
        int lc = min(max(l, 0), 1023);
        const unsigned short* kp = kb + (size_t)lc * 64 + ksel;
        short8 b0 = *reinterpret_cast<const short8*>(kp);
        short8 b1 = *reinterpret_cast<const short8*>(kp + 32);
        f32x4 a = f32x4{0.f, 0.f, 0.f, 0.f};
        a = __builtin_amdgcn_mfma_f32_16x16x32_bf16(af0, b0, a, 0, 0, 0);
        a = __builtin_amdgcn_mfma_f32_16x16x32_bf16(af1, b1, a, 0, 0, 0);
        acc[ni] = a;
    }

    // banded softmax: col c = ni*16+m, local row = wv*16 + q4*4 + reg
    const int rbase = wv * 16 + q4 * 4;
    float rs[4] = {0.f, 0.f, 0.f, 0.f};
#pragma unroll
    for (int ni = 0; ni < 12; ++ni) {
        const int c = ni * 16 + m;
#pragma unroll
        for (int reg = 0; reg < 4; ++reg) {
            const int rlw = rbase + reg;
            bool valid = (c >= rlw) && (c <= rlw + 127) && (c + t0 >= 127);
            float e = valid ? __expf(acc[ni][reg]) : 0.f;
            acc[ni][reg] = e;
            rs[reg] += e;
        }
    }
#pragma unroll
    for (int reg = 0; reg < 4; ++reg) {
#pragma unroll
        for (int mm = 1; mm < 16; mm <<= 1) rs[reg] += __shfl_xor(rs[reg], mm);
        rs[reg] = 1.0f / rs[reg];             // diagonal always valid -> > 0
    }
#pragma unroll
    for (int ni = 0; ni < 12; ++ni) {
        float cs = acc[ni][0] * rs[0] + acc[ni][1] * rs[1] +
                   acc[ni][2] * rs[2] + acc[ni][3] * rs[3];
        cs += __shfl_xor(cs, 16);
        cs += __shfl_xor(cs, 32);
        if (lane < 16) atomicAdd(&wloc[ni * 16 + m], cs);
    }
    __syncthreads();

    for (int c = tid; c < 192; c += 256) {
        int l = t0 - 127 + c;
        if (l >= 0 && l < 1024)
            atomicAdd(&w[(size_t)nh * 1024 + l], wloc[c]);
    }
}

// ---------------------------------------------------------------------------
// K2: apb[row][d] = bf16( w_scale(row) * sum_e values[row][e] * Wv[d][e] )
// ---------------------------------------------------------------------------
__global__ __launch_bounds__(256) void k_ap2(const float* __restrict__ values,
                                             const unsigned short* __restrict__ Wvb,
                                             const float* __restrict__ w,
                                             unsigned short* __restrict__ apb) {
    const int tid = threadIdx.x;
    const long R0 = (long)blockIdx.x * 64;    // 1024 blocks
    const int wv = tid >> 6, lane = tid & 63;
    const int m = lane & 15, ksel = (lane >> 4) * 8;

    const float* va = values + (R0 + wv * 16 + m) * 64;
    short8 af[2];
#pragma unroll
    for (int ch = 0; ch < 2; ++ch) {
        float4 x0 = *reinterpret_cast<const float4*>(va + ch * 32 + ksel);
        float4 x1 = *reinterpret_cast<const float4*>(va + ch * 32 + ksel + 4);
        short8 a;
        a[0] = (short)f2bf(x0.x); a[1] = (short)f2bf(x0.y);
        a[2] = (short)f2bf(x0.z); a[3] = (short)f2bf(x0.w);
        a[4] = (short)f2bf(x1.x); a[5] = (short)f2bf(x1.y);
        a[6] = (short)f2bf(x1.z); a[7] = (short)f2bf(x1.w);
        af[ch] = a;
    }

    f32x4 acc[4];
#pragma unroll
    for (int dc = 0; dc < 4; ++dc) {
        acc[dc] = f32x4{0.f, 0.f, 0.f, 0.f};
#pragma unroll
        for (int ch = 0; ch < 2; ++ch) {
            short8 bf = *reinterpret_cast<const short8*>(
                Wvb + (size_t)(dc * 16 + m) * 64 + ch * 32 + ksel);
            acc[dc] = __builtin_amdgcn_mfma_f32_16x16x32_bf16(af[ch], bf, acc[dc], 0, 0, 0);
        }
    }

    const long rowb = R0 + wv * 16 + (lane >> 4) * 4;
    float wf[4];
#pragma unroll
    for (int reg = 0; reg < 4; ++reg) {
        long rg = rowb + reg;
        int hh = (int)(rg & 15);
        int ll = (int)((rg >> 4) & 1023);
        int nn = (int)(rg >> 14);
        wf[reg] = w[((size_t)(nn * 16 + hh) << 10) + ll];
    }
#pragma unroll
    for (int dc = 0; dc < 4; ++dc)
#pragma unroll
        for (int reg = 0; reg < 4; ++reg)
            apb[(size_t)(rowb + reg) * 64 + dc * 16 + m] = f2bf(acc[dc][reg] * wf[reg]);
}

// ---------------------------------------------------------------------------
// K3: out = ap (4096x1024 bf16) @ Wo^T (bf16) + bo, f32 out.
// 128x64 tiles, 512 blocks (2 blocks/CU), strip-fast swizzle, BK=64 as two
// 128x32 halves. 2-phase double-buffer: stage kt+1 before computing kt,
// ONE __syncthreads per K-step (implicit vmcnt(0)+lgkmcnt(0) is the wait).
// LDS 48KB. MFMA k-order preserved -> bit-identical output. [R1-proven]
// ---------------------------------------------------------------------------
__global__ __launch_bounds__(256) void k_out_mfma(
    const unsigned short* __restrict__ apb,
    const unsigned short* __restrict__ wob,
    const float* __restrict__ bo,
    float* __restrict__ out) {
    __shared__ unsigned short As[2][2][128 * 32];   // [buf][half] 2 x 2 x 8 KB
    __shared__ unsigned short Bs[2][2][64 * 32];    // [buf][half] 2 x 2 x 4 KB

    const int tid  = threadIdx.x;
    const int wv   = tid >> 6;     // wave 0..3 -> m-rows wv*32..+31
    const int lane = tid & 63;
    const int m    = lane & 15;

    const int by = blockIdx.x & 31;   // row strip (swizzle: strip fast)
    const int bx = blockIdx.x >> 5;   // 16 col tiles (64 cols)
    const long arow0 = (long)by * 128;
    const int  bcol0 = bx * 64;

    f32x4 acc[2][4];
#pragma unroll
    for (int mi = 0; mi < 2; ++mi)
#pragma unroll
        for (int ni = 0; ni < 4; ++ni) acc[mi][ni] = f32x4{0.f, 0.f, 0.f, 0.f};

    const int r0s = tid >> 2;         // 0..63
    const int kks = (tid & 3) * 8;

    // stage one BK=64 tile (two 32-halves) into buffer `buf`
    auto stage = [&](int buf, int kt) {
        const int k0 = kt * 64;
#pragma unroll
        for (int hh = 0; hh < 2; ++hh) {
            const int kh = k0 + hh * 32;
#pragma unroll
            for (int i = 0; i < 2; ++i) {
                const unsigned short* g =
                    apb + (arow0 + i * 64 + r0s) * 1024 + kh + kks;
                __builtin_amdgcn_global_load_lds(
                    (const __attribute__((address_space(1))) unsigned int*)g,
                    (__attribute__((address_space(3))) unsigned int*)&As[buf][hh][i * 2048 + wv * 512],
                    16, 0, 0);
            }
            {
                const unsigned short* g =
                    wob + (size_t)(bcol0 + r0s) * 1024 + kh + kks;
                __builtin_amdgcn_global_load_lds(
                    (const __attribute__((address_space(1))) unsigned int*)g,
                    (__attribute__((address_space(3))) unsigned int*)&Bs[buf][hh][wv * 512],
                    16, 0, 0);
            }
        }
    };

    stage(0, 0);
    __syncthreads();                  // vmcnt(0): tile 0 landed

    int cur = 0;
    for (int kt = 0; kt < 16; ++kt) {
        if (kt < 15) stage(cur ^ 1, kt + 1);   // prefetch next tile (in flight)

        const int koff = (lane >> 4) * 8;
        const int rA = wv * 32 + m;
        short8 af[2][2], bf[4][2];
#pragma unroll
        for (int hh = 0; hh < 2; ++hh) {
#pragma unroll
            for (int mi = 0; mi < 2; ++mi)
                af[mi][hh] = *reinterpret_cast<const short8*>(
                    &As[cur][hh][(rA + mi * 16) * 32 + koff]);
#pragma unroll
            for (int ni = 0; ni < 4; ++ni)
                bf[ni][hh] = *reinterpret_cast<const short8*>(
                    &Bs[cur][hh][(ni * 16 + m) * 32 + koff]);
        }
#pragma unroll
        for (int mi = 0; mi < 2; ++mi)
#pragma unroll
            for (int ni = 0; ni < 4; ++ni) {
                acc[mi][ni] = __builtin_amdgcn_mfma_f32_16x16x32_bf16(
                    af[mi][0], bf[ni][0], acc[mi][ni], 0, 0, 0);
                acc[mi][ni] = __builtin_amdgcn_mfma_f32_16x16x32_bf16(
                    af[mi][1], bf[ni][1], acc[mi][ni], 0, 0, 0);
            }
        __syncthreads();              // drains vmcnt(0) (next tile) + lgkmcnt
        cur ^= 1;
    }

    const int colb = bcol0 + m;
    const int rowb = (int)arow0 + wv * 32 + (lane >> 4) * 4;
#pragma unroll
    for (int ni = 0; ni < 4; ++ni) {
        const int col = colb + ni * 16;
        const float bias = bo[col];
#pragma unroll
        for (int mi = 0; mi < 2; ++mi) {
            const int row = rowb + mi * 16;
#pragma unroll
            for (int r = 0; r < 4; ++r)
                out[(size_t)(row + r) * 1024 + col] = acc[mi][ni][r] + bias;
        }
    }
}

// ---------------------------------------------------------------------------
extern "C" void kernel_launch(void* const* d_in, const int* in_sizes, int n_in,
                              void* d_out, int out_size, void* d_ws, size_t ws_size,
                              hipStream_t stream) {
    const float* values = (const float*)d_in[0];
    const float* keys   = (const float*)d_in[1];
    const float* query  = (const float*)d_in[2];
    const float* Wv     = (const float*)d_in[4];
    const float* Wk     = (const float*)d_in[5];
    const float* Wq     = (const float*)d_in[6];
    const float* Wo     = (const float*)d_in[7];
    const float* bo     = (const float*)d_in[8];
    float* out = (float*)d_out;

    // workspace layout (~18.3 MB of the 256 MiB ws; no overlays — r3 lesson):
    float* w             = (float*)d_ws;                 // 65536 f32   (256 KB)
    unsigned short* Wvb  = (unsigned short*)(w + 65536); // 4096 bf16   (8 KB)
    unsigned short* wob  = Wvb + 4096;                   // 1M bf16     (2 MB)
    unsigned short* kk2p = wob + 1024 * 1024;            // 4M bf16     (8 MB)
    unsigned short* apb  = kk2p + 64 * 1024 * 64;        // 4M bf16     (8 MB)

    k_stage<<<2064, 256, 0, stream>>>(keys, Wq, Wk, Wv, (const float4*)Wo,
                                      kk2p, (ushort4*)wob, Wvb, w);
    k_w2<<<1024, 256, 0, stream>>>(query, kk2p, w);
    k_ap2<<<1024, 256, 0, stream>>>(values, Wvb, w, apb);
    k_out_mfma<<<512, 256, 0, stream>>>(apb, wob, bo, out);
}

// Round 4
// 150.414 us; speedup vs baseline: 1.0846x; 1.0484x over previous
//
#include <hip/hip_runtime.h>
#include <hip/hip_bf16.h>
#include <math.h>

// Problem constants: N=4, L=1024, D=1024, H=16, HD=64, HIST=128, SCALE=32
// Faithful-bug structure: attention[n,l,h,d] = (sum_q scores[n,h,q,l]) * v[n,l,h,d]
// => only column sums w[n,h,l] of softmax needed.
// Energy trick: E = Xq (Wq^T Wk/32) Xk^T = Xq . kk2^T with kk2 = K.(M^T).
// Round 14: 3-launch restructure.
//  K_A (k_fused): per (nh,tile) block recomputes its 192-row kk2 band
//    in-LDS from keys (M per-block, bit-identical math to old k_stage kp),
//    then QK^T + banded softmax + column sums -> wpart[tile][nh][192]
//    (plain stores, NO atomics, NO w pre-zeroing). Light blocks 1024..2063
//    do wob/Wvb conversion. Eliminates the kk2p 8MB HBM write + 8MB read
//    and one dispatch boundary.
//  K_B (k_ap2): V-proj; w gathered as sum of <=3 covering wpart tiles
//    (t in [l>>6, min(15,(l+127)>>6)], p = l-64t+127; 16-lane broadcast).
//  K_C (k_out): unchanged R1-proven 128x64/grid-512 2-phase dbuf.
//  Noise note: R1 vs R3 identical code measured 155.8 vs 157.7 -> +-2us.

using short8 = __attribute__((ext_vector_type(8))) short;
using f32x4  = __attribute__((ext_vector_type(4))) float;

__device__ __forceinline__ unsigned short f2bf(float x) {
    unsigned u = __float_as_uint(x);
    u += 0x7FFFu + ((u >> 16) & 1u);      // round-to-nearest-even
    return (unsigned short)(u >> 16);
}

// ---------------------------------------------------------------------------
// K_A (k_fused), grid 2064:
//  b 0..1023   : fused band-kk2 + QK^T + softmax colsums -> wpart[b][192]
//  b 1024..2047: wob = bf16(Wo)
//  b 2048..2063: Wvb = bf16(Wv)
// ---------------------------------------------------------------------------
__global__ __launch_bounds__(256) void k_fused(const float* __restrict__ keys,
                                               const float* __restrict__ query,
                                               const float* __restrict__ Wq,
                                               const float* __restrict__ Wk,
                                               const float* __restrict__ Wv,
                                               const float4* __restrict__ Wo4,
                                               float* __restrict__ wpart,
                                               ushort4* __restrict__ wob4,
                                               unsigned short* __restrict__ Wvb) {
    __shared__ unsigned short Ml[64 * 64];     // 8 KB  M[e][f] bf16
    __shared__ unsigned short band[192 * 72];  // 27 KB kk2 band, pad 72
    __shared__ float wloc[192];

    const int b = blockIdx.x, tid = threadIdx.x;

    if (b < 1024) {
        const int nh = b & 63, tile = b >> 6;
        const int t0 = tile * 64;
        const int h = nh & 15, n = nh >> 4;
        const int wv = tid >> 6, lane = tid & 63;
        const int m = lane & 15, q4 = lane >> 4, ksel = q4 * 8;

        if (tid < 192) wloc[tid] = 0.f;

        // early-issue query row loads (consumed after the band phase; no LDS
        // dependency, so latency hides under phases M and band)
        const float* qrow = query +
            ((size_t)(n * 1024 + t0 + wv * 16 + m)) * 1024 + h * 64;
        const float4 x0 = *reinterpret_cast<const float4*>(qrow + ksel);
        const float4 x1 = *reinterpret_cast<const float4*>(qrow + ksel + 4);
        const float4 x2 = *reinterpret_cast<const float4*>(qrow + 32 + ksel);
        const float4 x3 = *reinterpret_cast<const float4*>(qrow + 32 + ksel + 4);

        // ---- phase M: D[e][f] = sum_d Wq[d][e]*Wk[d][f], /32, bf16 ----
        // (identical math/order to the old k_stage M phase -> bit-identical M)
        {
            short8 aM0, aM1;
#pragma unroll
            for (int j = 0; j < 8; ++j) {
                aM0[j] = (short)f2bf(Wq[(ksel + j) * 64 + wv * 16 + m]);
                aM1[j] = (short)f2bf(Wq[(32 + ksel + j) * 64 + wv * 16 + m]);
            }
#pragma unroll
            for (int fc = 0; fc < 4; ++fc) {
                short8 bM0, bM1;
#pragma unroll
                for (int j = 0; j < 8; ++j) {
                    bM0[j] = (short)f2bf(Wk[(ksel + j) * 64 + fc * 16 + m]);
                    bM1[j] = (short)f2bf(Wk[(32 + ksel + j) * 64 + fc * 16 + m]);
                }
                f32x4 a = f32x4{0.f, 0.f, 0.f, 0.f};
                a = __builtin_amdgcn_mfma_f32_16x16x32_bf16(aM0, bM0, a, 0, 0, 0);
                a = __builtin_amdgcn_mfma_f32_16x16x32_bf16(aM1, bM1, a, 0, 0, 0);
#pragma unroll
                for (int r = 0; r < 4; ++r)
                    Ml[(wv * 16 + q4 * 4 + r) * 64 + fc * 16 + m] =
                        f2bf(a[r] * (1.0f / 32.0f));
            }
        }
        __syncthreads();

        // ---- phase band: band[p] = kk2[nh][clamp(t0-127+p)], p=0..191 ----
        // 3 groups of 64 rows; per group identical math to old k_stage kp
        // (same A-frag build, same ch-order MFMA, f2bf of acc) -> values
        // bit-identical to the old kk2p path.
#pragma unroll
        for (int grp = 0; grp < 3; ++grp) {
            const int pA = grp * 64 + wv * 16 + m;
            const int lrow = min(max(t0 - 127 + pA, 0), 1023);
            const float* ka = keys + ((size_t)(n * 1024 + lrow)) * 1024 + h * 64;
            short8 af[2];
#pragma unroll
            for (int ch = 0; ch < 2; ++ch) {
                float4 k0 = *reinterpret_cast<const float4*>(ka + ch * 32 + ksel);
                float4 k1 = *reinterpret_cast<const float4*>(ka + ch * 32 + ksel + 4);
                short8 a;
                a[0] = (short)f2bf(k0.x); a[1] = (short)f2bf(k0.y);
                a[2] = (short)f2bf(k0.z); a[3] = (short)f2bf(k0.w);
                a[4] = (short)f2bf(k1.x); a[5] = (short)f2bf(k1.y);
                a[6] = (short)f2bf(k1.z); a[7] = (short)f2bf(k1.w);
                af[ch] = a;
            }
            f32x4 acc[4];
#pragma unroll
            for (int fc = 0; fc < 4; ++fc) {
                acc[fc] = f32x4{0.f, 0.f, 0.f, 0.f};
#pragma unroll
                for (int ch = 0; ch < 2; ++ch) {
                    short8 bf = *reinterpret_cast<const short8*>(
                        &Ml[(fc * 16 + m) * 64 + ch * 32 + ksel]);
                    acc[fc] = __builtin_amdgcn_mfma_f32_16x16x32_bf16(af[ch], bf, acc[fc], 0, 0, 0);
                }
            }
            const int prow = grp * 64 + wv * 16 + q4 * 4;
#pragma unroll
            for (int reg = 0; reg < 4; ++reg)
#pragma unroll
                for (int fc = 0; fc < 4; ++fc)
                    band[(prow + reg) * 72 + fc * 16 + m] = f2bf(acc[fc][reg]);
        }
        __syncthreads();

        // ---- phase QK^T + banded softmax + column sums ----
        short8 af0, af1;
        af0[0] = (short)f2bf(x0.x); af0[1] = (short)f2bf(x0.y);
        af0[2] = (short)f2bf(x0.z); af0[3] = (short)f2bf(x0.w);
        af0[4] = (short)f2bf(x1.x); af0[5] = (short)f2bf(x1.y);
        af0[6] = (short)f2bf(x1.z); af0[7] = (short)f2bf(x1.w);
        af1[0] = (short)f2bf(x2.x); af1[1] = (short)f2bf(x2.y);
        af1[2] = (short)f2bf(x2.z); af1[3] = (short)f2bf(x2.w);
        af1[4] = (short)f2bf(x3.x); af1[5] = (short)f2bf(x3.y);
        af1[6] = (short)f2bf(x3.z); af1[7] = (short)f2bf(x3.w);

        f32x4 acc[12];
#pragma unroll
        for (int ni = 0; ni < 12; ++ni) {
            const unsigned short* kp_ = &band[(ni * 16 + m) * 72 + ksel];
            short8 b0 = *reinterpret_cast<const short8*>(kp_);
            short8 b1 = *reinterpret_cast<const short8*>(kp_ + 32);
            f32x4 a = f32x4{0.f, 0.f, 0.f, 0.f};
            a = __builtin_amdgcn_mfma_f32_16x16x32_bf16(af0, b0, a, 0, 0, 0);
            a = __builtin_amdgcn_mfma_f32_16x16x32_bf16(af1, b1, a, 0, 0, 0);
            acc[ni] = a;
        }

        const int rbase = wv * 16 + q4 * 4;
        float rs[4] = {0.f, 0.f, 0.f, 0.f};
#pragma unroll
        for (int ni = 0; ni < 12; ++ni) {
            const int c = ni * 16 + m;
#pragma unroll
            for (int reg = 0; reg < 4; ++reg) {
                const int rlw = rbase + reg;
                bool valid = (c >= rlw) && (c <= rlw + 127) && (c + t0 >= 127);
                float e = valid ? __expf(acc[ni][reg]) : 0.f;
                acc[ni][reg] = e;
                rs[reg] += e;
            }
        }
#pragma unroll
        for (int reg = 0; reg < 4; ++reg) {
#pragma unroll
            for (int mm = 1; mm < 16; mm <<= 1) rs[reg] += __shfl_xor(rs[reg], mm);
            rs[reg] = 1.0f / rs[reg];         // diagonal always valid -> > 0
        }
#pragma unroll
        for (int ni = 0; ni < 12; ++ni) {
            float cs = acc[ni][0] * rs[0] + acc[ni][1] * rs[1] +
                       acc[ni][2] * rs[2] + acc[ni][3] * rs[3];
            cs += __shfl_xor(cs, 16);
            cs += __shfl_xor(cs, 32);
            if (lane < 16) atomicAdd(&wloc[ni * 16 + m], cs);
        }
        __syncthreads();

        if (tid < 192) wpart[(size_t)b * 192 + tid] = wloc[tid];
    } else if (b < 2048) {
        // ---------------- Wo -> bf16 ----------------
        const int bb = b - 1024;
        int idx = bb * 256 + tid;             // 262144 float4s
        float4 v = Wo4[idx];
        ushort4 o; o.x = f2bf(v.x); o.y = f2bf(v.y);
        o.z = f2bf(v.z); o.w = f2bf(v.w);
        wob4[idx] = o;
    } else {
        // ---------------- Wv -> bf16 ----------------
        int idx = (b - 2048) * 256 + tid;     // 4096
        Wvb[idx] = f2bf(Wv[idx]);
    }
}

// ---------------------------------------------------------------------------
// K_B: apb[row][d] = bf16( w_scale(row) * sum_e values[row][e] * Wv[d][e] )
// w_scale gathered from wpart: tiles t in [l>>6, min(15,(l+127)>>6)],
// band position p = l - 64t + 127 (always in [0,191]). 16-lane broadcast.
// ---------------------------------------------------------------------------
__global__ __launch_bounds__(256) void k_ap2(const float* __restrict__ values,
                                             const unsigned short* __restrict__ Wvb,
                                             const float* __restrict__ wpart,
                                             unsigned short* __restrict__ apb) {
    const int tid = threadIdx.x;
    const long R0 = (long)blockIdx.x * 64;    // 1024 blocks
    const int wv = tid >> 6, lane = tid & 63;
    const int m = lane & 15, ksel = (lane >> 4) * 8;

    const float* va = values + (R0 + wv * 16 + m) * 64;
    short8 af[2];
#pragma unroll
    for (int ch = 0; ch < 2; ++ch) {
        float4 x0 = *reinterpret_cast<const float4*>(va + ch * 32 + ksel);
        float4 x1 = *reinterpret_cast<const float4*>(va + ch * 32 + ksel + 4);
        short8 a;
        a[0] = (short)f2bf(x0.x); a[1] = (short)f2bf(x0.y);
        a[2] = (short)f2bf(x0.z); a[3] = (short)f2bf(x0.w);
        a[4] = (short)f2bf(x1.x); a[5] = (short)f2bf(x1.y);
        a[6] = (short)f2bf(x1.z); a[7] = (short)f2bf(x1.w);
        af[ch] = a;
    }

    f32x4 acc[4];
#pragma unroll
    for (int dc = 0; dc < 4; ++dc) {
        acc[dc] = f32x4{0.f, 0.f, 0.f, 0.f};
#pragma unroll
        for (int ch = 0; ch < 2; ++ch) {
            short8 bf = *reinterpret_cast<const short8*>(
                Wvb + (size_t)(dc * 16 + m) * 64 + ch * 32 + ksel);
            acc[dc] = __builtin_amdgcn_mfma_f32_16x16x32_bf16(af[ch], bf, acc[dc], 0, 0, 0);
        }
    }

    const long rowb = R0 + wv * 16 + (lane >> 4) * 4;
    float wf[4];
#pragma unroll
    for (int reg = 0; reg < 4; ++reg) {
        long rg = rowb + reg;
        int hh = (int)(rg & 15);
        int ll = (int)((rg >> 4) & 1023);
        int nn = (int)(rg >> 14);
        int nhI = nn * 16 + hh;
        int tmax = min(15, (ll + 127) >> 6);
        float s = 0.f;
        for (int t = ll >> 6; t <= tmax; ++t)
            s += wpart[(size_t)((t << 6) + nhI) * 192 + (ll - (t << 6) + 127)];
        wf[reg] = s;
    }
#pragma unroll
    for (int dc = 0; dc < 4; ++dc)
#pragma unroll
        for (int reg = 0; reg < 4; ++reg)
            apb[(size_t)(rowb + reg) * 64 + dc * 16 + m] = f2bf(acc[dc][reg] * wf[reg]);
}

// ---------------------------------------------------------------------------
// K_C: out = ap (4096x1024 bf16) @ Wo^T (bf16) + bo, f32 out.
// 128x64 tiles, 512 blocks (2 blocks/CU), strip-fast swizzle, BK=64 as two
// 128x32 halves. 2-phase double-buffer: stage kt+1 before computing kt,
// ONE __syncthreads per K-step (implicit vmcnt(0)+lgkmcnt(0) is the wait).
// LDS 48KB. MFMA k-order preserved -> bit-identical output. [R1-proven]
// ---------------------------------------------------------------------------
__global__ __launch_bounds__(256) void k_out_mfma(
    const unsigned short* __restrict__ apb,
    const unsigned short* __restrict__ wob,
    const float* __restrict__ bo,
    float* __restrict__ out) {
    __shared__ unsigned short As[2][2][128 * 32];   // [buf][half] 2 x 2 x 8 KB
    __shared__ unsigned short Bs[2][2][64 * 32];    // [buf][half] 2 x 2 x 4 KB

    const int tid  = threadIdx.x;
    const int wv   = tid >> 6;     // wave 0..3 -> m-rows wv*32..+31
    const int lane = tid & 63;
    const int m    = lane & 15;

    const int by = blockIdx.x & 31;   // row strip (swizzle: strip fast)
    const int bx = blockIdx.x >> 5;   // 16 col tiles (64 cols)
    const long arow0 = (long)by * 128;
    const int  bcol0 = bx * 64;

    f32x4 acc[2][4];
#pragma unroll
    for (int mi = 0; mi < 2; ++mi)
#pragma unroll
        for (int ni = 0; ni < 4; ++ni) acc[mi][ni] = f32x4{0.f, 0.f, 0.f, 0.f};

    const int r0s = tid >> 2;         // 0..63
    const int kks = (tid & 3) * 8;

    // stage one BK=64 tile (two 32-halves) into buffer `buf`
    auto stage = [&](int buf, int kt) {
        const int k0 = kt * 64;
#pragma unroll
        for (int hh = 0; hh < 2; ++hh) {
            const int kh = k0 + hh * 32;
#pragma unroll
            for (int i = 0; i < 2; ++i) {
                const unsigned short* g =
                    apb + (arow0 + i * 64 + r0s) * 1024 + kh + kks;
                __builtin_amdgcn_global_load_lds(
                    (const __attribute__((address_space(1))) unsigned int*)g,
                    (__attribute__((address_space(3))) unsigned int*)&As[buf][hh][i * 2048 + wv * 512],
                    16, 0, 0);
            }
            {
                const unsigned short* g =
                    wob + (size_t)(bcol0 + r0s) * 1024 + kh + kks;
                __builtin_amdgcn_global_load_lds(
                    (const __attribute__((address_space(1))) unsigned int*)g,
                    (__attribute__((address_space(3))) unsigned int*)&Bs[buf][hh][wv * 512],
                    16, 0, 0);
            }
        }
    };

    stage(0, 0);
    __syncthreads();                  // vmcnt(0): tile 0 landed

    int cur = 0;
    for (int kt = 0; kt < 16; ++kt) {
        if (kt < 15) stage(cur ^ 1, kt + 1);   // prefetch next tile (in flight)

        const int koff = (lane >> 4) * 8;
        const int rA = wv * 32 + m;
        short8 af[2][2], bf[4][2];
#pragma unroll
        for (int hh = 0; hh < 2; ++hh) {
#pragma unroll
            for (int mi = 0; mi < 2; ++mi)
                af[mi][hh] = *reinterpret_cast<const short8*>(
                    &As[cur][hh][(rA + mi * 16) * 32 + koff]);
#pragma unroll
            for (int ni = 0; ni < 4; ++ni)
                bf[ni][hh] = *reinterpret_cast<const short8*>(
                    &Bs[cur][hh][(ni * 16 + m) * 32 + koff]);
        }
#pragma unroll
        for (int mi = 0; mi < 2; ++mi)
#pragma unroll
            for (int ni = 0; ni < 4; ++ni) {
                acc[mi][ni] = __builtin_amdgcn_mfma_f32_16x16x32_bf16(
                    af[mi][0], bf[ni][0], acc[mi][ni], 0, 0, 0);
                acc[mi][ni] = __builtin_amdgcn_mfma_f32_16x16x32_bf16(
                    af[mi][1], bf[ni][1], acc[mi][ni], 0, 0, 0);
            }
        __syncthreads();              // drains vmcnt(0) (next tile) + lgkmcnt
        cur ^= 1;
    }

    const int colb = bcol0 + m;
    const int rowb = (int)arow0 + wv * 32 + (lane >> 4) * 4;
#pragma unroll
    for (int ni = 0; ni < 4; ++ni) {
        const int col = colb + ni * 16;
        const float bias = bo[col];
#pragma unroll
        for (int mi = 0; mi < 2; ++mi) {
            const int row = rowb + mi * 16;
#pragma unroll
            for (int r = 0; r < 4; ++r)
                out[(size_t)(row + r) * 1024 + col] = acc[mi][ni][r] + bias;
        }
    }
}

// ---------------------------------------------------------------------------
extern "C" void kernel_launch(void* const* d_in, const int* in_sizes, int n_in,
                              void* d_out, int out_size, void* d_ws, size_t ws_size,
                              hipStream_t stream) {
    const float* values = (const float*)d_in[0];
    const float* keys   = (const float*)d_in[1];
    const float* query  = (const float*)d_in[2];
    const float* Wv     = (const float*)d_in[4];
    const float* Wk     = (const float*)d_in[5];
    const float* Wq     = (const float*)d_in[6];
    const float* Wo     = (const float*)d_in[7];
    const float* bo     = (const float*)d_in[8];
    float* out = (float*)d_out;

    // workspace layout (~10.8 MB of the 256 MiB ws; no overlays):
    float* wpart         = (float*)d_ws;                   // 1024*192 f32 (768 KB)
    unsigned short* Wvb  = (unsigned short*)(wpart + 196608); // 4096 bf16 (8 KB)
    unsigned short* wob  = Wvb + 4096;                     // 1M bf16     (2 MB)
    unsigned short* apb  = wob + 1024 * 1024;              // 4M bf16     (8 MB)

    k_fused<<<2064, 256, 0, stream>>>(keys, query, Wq, Wk, Wv, (const float4*)Wo,
                                      wpart, (ushort4*)wob, Wvb);
    k_ap2<<<1024, 256, 0, stream>>>(values, Wvb, wpart, apb);
    k_out_mfma<<<512, 256, 0, stream>>>(apb, wob, bo, out);
}